// Round 4
// baseline (14.547 us; speedup 1.0000x reference)
//
#include <hip/hip_runtime.h>
#include <cmath>

#define B_DIM 64
#define S_DIM 512
#define H_DIM 768
#define MAX_DEPTH 48
#define EPS 1e-7f

// Single dispatch: 256 blocks x 768 threads (12 waves). Wave w of block bid
// handles task idx = bid*12 + w  (0..3071), i.e. (b,l) = (idx/48, idx%48).
// All loads issued unconditionally (no branch gating the node load) to keep
// the dependent-miss chain at 2 levels. Mask applied arithmetically at the
// end. Block reduces 12 wave partials in LDS; one atomicAdd per block into
// out[0], which a memset node zeroes first.
__global__ __launch_bounds__(768) void kt_fused_atomic_kernel(
    const float* __restrict__ outputs,      // (B, S, H) -- only token 0 used
    const float* __restrict__ embedding,    // (N_NODES, H)
    const int*   __restrict__ path_nodes,   // (B, MAX_DEPTH)
    const int*   __restrict__ path_signs,   // (B, MAX_DEPTH)
    const int*   __restrict__ path_lengths, // (B,)
    float*       __restrict__ out)          // scalar accumulator (pre-zeroed)
{
    const int lane = threadIdx.x & 63;
    const int wid  = threadIdx.x >> 6;               // 0..11
    const int idx  = blockIdx.x * 12 + wid;          // 0..3071
    const int b    = idx / MAX_DEPTH;
    const int l    = idx % MAX_DEPTH;

    // Independent loads -- all issue immediately, overlap their latencies.
    const int node = path_nodes[idx];
    const int len  = path_lengths[b];
    const int sg   = path_signs[idx];

    const float4* __restrict__ e4 =
        (const float4*)(embedding + (size_t)node * H_DIM);
    const float4* __restrict__ h4 =
        (const float4*)(outputs + (size_t)b * S_DIM * H_DIM);

    float acc = 0.0f;
    #pragma unroll
    for (int i = 0; i < 3; ++i) {
        const int j = lane + i * 64;
        float4 a = e4[j];
        float4 c = h4[j];
        acc += a.x * c.x + a.y * c.y + a.z * c.z + a.w * c.w;
    }
    #pragma unroll
    for (int off = 32; off > 0; off >>= 1)
        acc += __shfl_down(acc, off, 64);

    __shared__ float partial[12];
    if (lane == 0) {
        const float sgn  = (float)(2 * sg - 1);
        const float x    = sgn * acc;                // full dot on lane 0
        const float sig  = 1.0f / (1.0f + __expf(-x));
        const float term = __logf(sig + EPS);
        const float scaled = term * (-1.0f / ((float)len * (float)B_DIM));
        partial[wid] = (l < len) ? scaled : 0.0f;
    }
    __syncthreads();
    if (threadIdx.x == 0) {
        float s = 0.0f;
        #pragma unroll
        for (int w = 0; w < 12; ++w) s += partial[w];
        atomicAdd(out, s);
    }
}

extern "C" void kernel_launch(void* const* d_in, const int* in_sizes, int n_in,
                              void* d_out, int out_size, void* d_ws, size_t ws_size,
                              hipStream_t stream) {
    const float* outputs      = (const float*)d_in[0];
    const float* embedding    = (const float*)d_in[1];
    const int*   path_nodes   = (const int*)d_in[2];
    const int*   path_signs   = (const int*)d_in[3];
    const int*   path_lengths = (const int*)d_in[4];
    float*       out          = (float*)d_out;

    hipMemsetAsync(out, 0, sizeof(float), stream);   // capturable memset node
    kt_fused_atomic_kernel<<<256, 768, 0, stream>>>(
        outputs, embedding, path_nodes, path_signs, path_lengths, out);
}

// Round 5
// 11.257 us; speedup vs baseline: 1.2923x; 1.2923x over previous
//
#include <hip/hip_runtime.h>
#include <cmath>

#define B_DIM 64
#define S_DIM 512
#define H_DIM 768
#define MAX_DEPTH 48
#define EPS 1e-7f

// Stage 1: one 64-lane wave per (b,l) task, 3072 blocks.
// Scalar loads (node, len, sign) issue unconditionally in parallel -> the
// dependent-miss chain is max(path loads) -> e-row (2 levels, not 3).
// Masked tasks exit before the vector loads (halves vector traffic, avg
// len ~ 24.5/48). Term is pre-scaled by -1/(len*B) so stage 2 is a raw sum.
__global__ __launch_bounds__(64) void kt_dots_kernel(
    const float* __restrict__ outputs,      // (B, S, H) -- only token 0 used
    const float* __restrict__ embedding,    // (N_NODES, H)
    const int*   __restrict__ path_nodes,   // (B, MAX_DEPTH)
    const int*   __restrict__ path_signs,   // (B, MAX_DEPTH)
    const int*   __restrict__ path_lengths, // (B,)
    float*       __restrict__ terms)        // (B*MAX_DEPTH,) pre-scaled terms
{
    const int idx  = blockIdx.x;            // 0 .. B*MAX_DEPTH-1
    const int b    = idx / MAX_DEPTH;
    const int l    = idx % MAX_DEPTH;
    const int lane = threadIdx.x;           // 0..63

    // Independent scalar loads -- all issue immediately (uniform -> s_load).
    const int node = path_nodes[idx];
    const int len  = path_lengths[b];
    const int sg   = path_signs[idx];

    if (l >= len) {
        if (lane == 0) terms[idx] = 0.0f;
        return;
    }

    const float4* __restrict__ e4 = (const float4*)(embedding + (size_t)node * H_DIM);
    const float4* __restrict__ h4 = (const float4*)(outputs + (size_t)b * S_DIM * H_DIM);

    float acc = 0.0f;
    #pragma unroll
    for (int i = 0; i < 3; ++i) {
        const int j = lane + i * 64;
        float4 a = e4[j];
        float4 c = h4[j];
        acc += a.x * c.x + a.y * c.y + a.z * c.z + a.w * c.w;
    }

    #pragma unroll
    for (int off = 32; off > 0; off >>= 1)
        acc += __shfl_down(acc, off, 64);

    if (lane == 0) {
        const float sgn = (float)(2 * sg - 1);
        const float x   = sgn * acc;               // full dot on lane 0
        const float sig = 1.0f / (1.0f + __expf(-x));
        terms[idx] = __logf(sig + EPS) * (-1.0f / ((float)len * (float)B_DIM));
    }
}

// Stage 2: single wave; pure sum of 3072 pre-scaled floats.
// Each lane: 12 independent float4 loads (coalesced), sum 48 values,
// butterfly reduce, lane 0 stores the final scalar directly.
__global__ __launch_bounds__(64) void kt_reduce_kernel(
    const float* __restrict__ terms,        // (B*MAX_DEPTH,)
    float*       __restrict__ out)          // scalar
{
    const int lane = threadIdx.x;
    const float4* __restrict__ t4 = (const float4*)terms;

    float s = 0.0f;
    #pragma unroll
    for (int i = 0; i < 12; ++i) {          // 12 * 64 = 768 float4 = 3072 floats
        float4 v = t4[lane + i * 64];
        s += v.x + v.y + v.z + v.w;
    }

    #pragma unroll
    for (int off = 32; off > 0; off >>= 1)
        s += __shfl_down(s, off, 64);

    if (lane == 0) out[0] = s;              // already negated & /(len*B)
}

extern "C" void kernel_launch(void* const* d_in, const int* in_sizes, int n_in,
                              void* d_out, int out_size, void* d_ws, size_t ws_size,
                              hipStream_t stream) {
    const float* outputs      = (const float*)d_in[0];
    const float* embedding    = (const float*)d_in[1];
    const int*   path_nodes   = (const int*)d_in[2];
    const int*   path_signs   = (const int*)d_in[3];
    const int*   path_lengths = (const int*)d_in[4];
    float*       out          = (float*)d_out;
    float*       terms        = (float*)d_ws;   // B*MAX_DEPTH floats = 12 KiB

    kt_dots_kernel<<<B_DIM * MAX_DEPTH, 64, 0, stream>>>(
        outputs, embedding, path_nodes, path_signs, path_lengths, terms);
    kt_reduce_kernel<<<1, 64, 0, stream>>>(terms, out);
}